// Round 1
// baseline (150.142 us; speedup 1.0000x reference)
//
#include <hip/hip_runtime.h>
#include <hip/hip_bf16.h>

// out[i] = 0.999f * a[i*K + (int)z[i*D + attr_index]]
// B = 4194304, D = 32, K = 16, attr_index read from d_in[2] (scalar int array).

#define D_DIM 32
#define K_DIM 16
#define SCALE 0.999f

__global__ __launch_bounds__(256) void gather_valuation_kernel(
    const float* __restrict__ z,
    const float* __restrict__ a,
    const int* __restrict__ attr_p,
    float* __restrict__ out,
    int B)
{
    const int attr = attr_p[0];   // scalar, L2-cached broadcast
    int i = blockIdx.x * blockDim.x + threadIdx.x;
    const int stride = gridDim.x * blockDim.x;
    for (; i < B; i += stride) {
        // z column holds small non-negative integers stored as floats
        const int idx = (int)z[i * D_DIM + attr];
        out[i] = a[i * K_DIM + idx] * SCALE;
    }
}

extern "C" void kernel_launch(void* const* d_in, const int* in_sizes, int n_in,
                              void* d_out, int out_size, void* d_ws, size_t ws_size,
                              hipStream_t stream)
{
    const float* z    = (const float*)d_in[0];
    const float* a    = (const float*)d_in[1];
    const int*   attr = (const int*)d_in[2];
    float*       out  = (float*)d_out;

    const int B = out_size;  // 4194304

    const int block = 256;
    const int grid  = 2048;  // 8 blocks/CU on 256 CUs; grid-stride covers the rest

    gather_valuation_kernel<<<grid, block, 0, stream>>>(z, a, attr, out, B);
}